// Round 1
// baseline (206.688 us; speedup 1.0000x reference)
//
#include <hip/hip_runtime.h>

#define BB 8
#define LL 2048
#define DD 512
#define NN 64
#define TT 64
#define CC 32   // LL/TT chunks

__device__ __forceinline__ float2 cmul(float2 a, float2 b) {
  return make_float2(a.x*b.x - a.y*b.y, a.x*b.y + a.y*b.x);
}

// ---------------------------------------------------------------------------
// K1: per-(d) setup. 64 threads = one wave, lane = n.
// Computes Abar=exp(dt*A), Bbar=dt*(Abar-1+eps)/(dt*A+eps), P=Abar^T,
// and K_locT[m][d] = Re(sum_n C*Abar^m*Bbar) for m=0..T-1 (transposed layout
// so the conv kernel can load it coalesced).
// ---------------------------------------------------------------------------
__global__ __launch_bounds__(64) void k1_setup(
    const float* __restrict__ A_re, const float* __restrict__ A_im,
    const float* __restrict__ C_re, const float* __restrict__ C_im,
    const float* __restrict__ log_dt,
    float2* __restrict__ Abar, float2* __restrict__ Bbar,
    float2* __restrict__ P, float* __restrict__ KlocT) {
  int d = blockIdx.x, n = threadIdx.x;
  int idx = d * NN + n;
  float dt  = expf(log_dt[d]);
  float dre = dt * A_re[idx], dim = dt * A_im[idx];
  float er  = expf(dre);
  float abr = er * cosf(dim), abi = er * sinf(dim);
  const float eps = 1e-8f;
  float nre = abr - 1.0f + eps, nim = abi;
  float qre = dre + eps,        qim = dim;
  float inv = 1.0f / (qre*qre + qim*qim);
  float bbr = dt * (nre*qre + nim*qim) * inv;
  float bbi = dt * (nim*qre - nre*qim) * inv;
  Abar[idx] = make_float2(abr, abi);
  Bbar[idx] = make_float2(bbr, bbi);
  float erT = expf((float)TT * dre);
  float thT = (float)TT * dim;
  P[idx] = make_float2(erT * cosf(thT), erT * sinf(thT));
  // K_loc[m] = Re(sum_n C * Abar^m * Bbar)
  float ccr = C_re[idx], cci = C_im[idx];
  float tre = ccr*bbr - cci*bbi;
  float tim = ccr*bbi + cci*bbr;
  for (int m = 0; m < TT; ++m) {
    float v = tre;
    #pragma unroll
    for (int off = 32; off > 0; off >>= 1) v += __shfl_down(v, off, 64);
    if (n == 0) KlocT[m * DD + d] = v;
    float t2 = tre*abr - tim*abi;
    tim = tre*abi + tim*abr;
    tre = t2;
  }
}

// ---------------------------------------------------------------------------
// K2a: Z_c[n] = sum_s Abar^(T-1-s)*Bbar * u[cT+s]   for all 32 chunks.
// One block per (b,d); W (32KB) built once in LDS, reused by all chunks.
// b = blockIdx%8 so each XCD's L2 caches one batch's u slice (strided reads).
// ---------------------------------------------------------------------------
__global__ __launch_bounds__(256) void k2a_z(
    const float* __restrict__ u, const float2* __restrict__ Abar,
    const float2* __restrict__ Bbar, float2* __restrict__ Z) {
  int bid = blockIdx.x;
  int b = bid & 7, d = bid >> 3;
  int tid = threadIdx.x;
  int n = tid & 63, cg = tid >> 6;            // 4 chunk-groups
  __shared__ float2 Wl[TT][NN];               // 32 KB
  __shared__ float  ul[LL];                   // 8 KB
  for (int i = tid; i < LL; i += 256)
    ul[i] = u[((size_t)b * LL + i) * DD + d];
  if (tid < NN) {
    float2 a = Abar[d * NN + tid];
    float2 w = Bbar[d * NN + tid];
    for (int s = TT - 1; s >= 0; --s) { Wl[s][tid] = w; w = cmul(w, a); }
  }
  __syncthreads();
  for (int k = 0; k < CC / 4; ++k) {
    int c = cg * (CC / 4) + k;
    float zre = 0.f, zim = 0.f;
    const float* up = &ul[c * TT];
    #pragma unroll
    for (int s = 0; s < TT; ++s) {
      float uv = up[s];                       // LDS broadcast
      float2 w = Wl[s][n];                    // conflict-free
      zre = fmaf(w.x, uv, zre);
      zim = fmaf(w.y, uv, zim);
    }
    Z[((size_t)(b * CC + c) * DD + d) * NN + n] = make_float2(zre, zim);
  }
}

// ---------------------------------------------------------------------------
// K2b: in-place chunk scan. SZ holds Z_c on entry, S_c (state BEFORE chunk c)
// on exit: read z=Z_c, overwrite slot with S_c, S_{c+1} = P*S_c + z.
// ---------------------------------------------------------------------------
__global__ __launch_bounds__(64) void k2b_scan(
    const float2* __restrict__ P, float2* __restrict__ SZ) {
  int bid = blockIdx.x;
  int b = bid & 7, d = bid >> 3;
  int n = threadIdx.x;
  float2 p = P[d * NN + n];
  float2 s = make_float2(0.f, 0.f);
  for (int c = 0; c < CC; ++c) {
    size_t off = ((size_t)(b * CC + c) * DD + d) * NN + n;
    float2 z = SZ[off];
    SZ[off] = s;
    float2 ps = cmul(p, s);
    s = make_float2(ps.x + z.x, ps.y + z.y);
  }
}

// ---------------------------------------------------------------------------
// K3a: cross term y_cross[(b,c), r] = Re(sum_n C*Abar^(r+1) * S_c[n]) as a
// per-d GEMM. One block per d; 256 threads = 256 (b,c) pairs; G (32KB) built
// in LDS, read as broadcast. acc[64] stays in registers (fully unrolled).
// Output layout ycross[d][(b*CC+c)][r] (contiguous per thread).
// ---------------------------------------------------------------------------
__global__ __launch_bounds__(256) void k3a_cross(
    const float2* __restrict__ Abar, const float* __restrict__ C_re,
    const float* __restrict__ C_im, const float2* __restrict__ S,
    float* __restrict__ ycross) {
  int d = blockIdx.x, tid = threadIdx.x;
  __shared__ float2 Gl[TT][NN];               // 32 KB: G[r][n] = C*Abar^(r+1)
  if (tid < NN) {
    int n = tid;
    float2 a = Abar[d * NN + n];
    float2 g = cmul(make_float2(C_re[d*NN+n], C_im[d*NN+n]), a);
    for (int r = 0; r < TT; ++r) { Gl[r][n] = g; g = cmul(g, a); }
  }
  __syncthreads();
  float acc[TT];
  #pragma unroll
  for (int r = 0; r < TT; ++r) acc[r] = 0.f;
  const float2* Srow = S + ((size_t)tid * DD + d) * NN;  // tid = b*CC+c
  for (int n0 = 0; n0 < NN; n0 += 8) {
    float2 sv[8];
    #pragma unroll
    for (int k = 0; k < 8; ++k) sv[k] = Srow[n0 + k];
    #pragma unroll
    for (int r = 0; r < TT; ++r) {
      float av = acc[r];
      #pragma unroll
      for (int k = 0; k < 8; ++k) {
        float2 g = Gl[r][n0 + k];             // broadcast read
        av = fmaf(g.x, sv[k].x, av);
        av = fmaf(-g.y, sv[k].y, av);
      }
      acc[r] = av;
    }
  }
  float* yp = ycross + ((size_t)d * (BB*CC) + tid) * TT;
  #pragma unroll
  for (int r = 0; r < TT; r += 4)
    *(float4*)(yp + r) = make_float4(acc[r], acc[r+1], acc[r+2], acc[r+3]);
}

// ---------------------------------------------------------------------------
// K3b: local causal conv (64 taps) + add cross term, write y coalesced.
// Block per (b, c, d-tile of 64). ycross staged through padded LDS to turn
// its strided global layout into conflict-free reads.
// ---------------------------------------------------------------------------
__global__ __launch_bounds__(256) void k3b_out(
    const float* __restrict__ u, const float* __restrict__ KlocT,
    const float* __restrict__ ycross, float* __restrict__ y) {
  int bid = blockIdx.x;
  int d8 = bid & 7;
  int c  = (bid >> 3) & (CC - 1);
  int b  = bid >> 8;
  int d0 = d8 * 64;
  int tid = threadIdx.x;
  int dd = tid & 63, rg = tid >> 6;
  __shared__ float ul2[TT][64];               // 16 KB
  __shared__ float Ktl[TT][64];               // 16 KB
  __shared__ float ycl[64][65];               // 16.6 KB, pad breaks conflicts
  for (int i = tid; i < TT * 64; i += 256) {
    int s = i >> 6, e = i & 63;
    ul2[s][e] = u[((size_t)b * LL + c * TT + s) * DD + d0 + e];
    Ktl[s][e] = KlocT[s * DD + d0 + e];
  }
  for (int i = tid; i < 64 * TT; i += 256) {
    int e = i >> 6, r = i & 63;
    ycl[e][r] = ycross[((size_t)(d0 + e) * (BB*CC) + b * CC + c) * TT + r];
  }
  __syncthreads();
  #pragma unroll 1
  for (int k = 0; k < 16; ++k) {
    int r = rg + 4 * k;                       // wave-uniform r
    float a = ycl[dd][r];
    for (int m = 0; m <= r; ++m)
      a = fmaf(Ktl[m][dd], ul2[r - m][dd], a);
    y[((size_t)b * LL + c * TT + r) * DD + d0 + dd] = a;
  }
}

extern "C" void kernel_launch(void* const* d_in, const int* in_sizes, int n_in,
                              void* d_out, int out_size, void* d_ws, size_t ws_size,
                              hipStream_t stream) {
  const float* u      = (const float*)d_in[0];
  const float* A_re   = (const float*)d_in[1];
  const float* A_im   = (const float*)d_in[2];
  const float* C_re   = (const float*)d_in[3];
  const float* C_im   = (const float*)d_in[4];
  const float* log_dt = (const float*)d_in[5];
  float* y  = (float*)d_out;
  float* ws = (float*)d_ws;

  // workspace layout (floats):
  //   SZ     : B*C*D*N float2 = 16,777,216 floats (67.1 MB)
  //   ycross : D*B*C*T        =  8,388,608 floats (33.6 MB)
  //   Abar/Bbar/P : 3 * 65,536 floats; KlocT: 32,768 floats  (~97 MB total)
  float2* SZ     = (float2*)ws;
  float*  ycross = ws + (size_t)2 * BB * CC * DD * NN;
  float2* Abar   = (float2*)(ycross + (size_t)DD * BB * CC * TT);
  float2* Bbar   = Abar + DD * NN;
  float2* P      = Bbar + DD * NN;
  float*  KlocT  = (float*)(P + DD * NN);

  k1_setup <<<DD,      64, 0, stream>>>(A_re, A_im, C_re, C_im, log_dt,
                                        Abar, Bbar, P, KlocT);
  k2a_z    <<<BB * DD, 256, 0, stream>>>(u, Abar, Bbar, SZ);
  k2b_scan <<<BB * DD, 64,  0, stream>>>(P, SZ);
  k3a_cross<<<DD,      256, 0, stream>>>(Abar, C_re, C_im, SZ, ycross);
  k3b_out  <<<BB * CC * (DD/64), 256, 0, stream>>>(u, KlocT, ycross, y);
}

// Round 2
// 157.012 us; speedup vs baseline: 1.3164x; 1.3164x over previous
//
#include <hip/hip_runtime.h>

#define BB 8
#define LL 2048
#define DD 512
#define NN 64
#define TT 64
#define CC 32   // LL/TT chunks

__device__ __forceinline__ float2 cmul(float2 a, float2 b) {
  return make_float2(a.x*b.x - a.y*b.y, a.x*b.y + a.y*b.x);
}

// ---------------------------------------------------------------------------
// K1: per-d setup. 64 threads = one wave, lane = n.
// Abar=exp(dt*A), Bbar=dt*(Abar-1+eps)/(dt*A+eps),
// K_locT[m][d] = Re(sum_n C*Abar^m*Bbar), m=0..63 (transposed for coalescing).
// ---------------------------------------------------------------------------
__global__ __launch_bounds__(64) void k1_setup(
    const float* __restrict__ A_re, const float* __restrict__ A_im,
    const float* __restrict__ C_re, const float* __restrict__ C_im,
    const float* __restrict__ log_dt,
    float2* __restrict__ Abar, float2* __restrict__ Bbar,
    float* __restrict__ KlocT) {
  int d = blockIdx.x, n = threadIdx.x;
  int idx = d * NN + n;
  float dt  = expf(log_dt[d]);
  float dre = dt * A_re[idx], dim = dt * A_im[idx];
  float er  = expf(dre);
  float abr = er * cosf(dim), abi = er * sinf(dim);
  const float eps = 1e-8f;
  float nre = abr - 1.0f + eps, nim = abi;
  float qre = dre + eps,        qim = dim;
  float inv = 1.0f / (qre*qre + qim*qim);
  float bbr = dt * (nre*qre + nim*qim) * inv;
  float bbi = dt * (nim*qre - nre*qim) * inv;
  Abar[idx] = make_float2(abr, abi);
  Bbar[idx] = make_float2(bbr, bbi);
  float ccr = C_re[idx], cci = C_im[idx];
  float tre = ccr*bbr - cci*bbi;
  float tim = ccr*bbi + cci*bbr;
  for (int m = 0; m < TT; ++m) {
    float v = tre;
    #pragma unroll
    for (int off = 32; off > 0; off >>= 1) v += __shfl_down(v, off, 64);
    if (n == 0) KlocT[m * DD + d] = v;
    float t2 = tre*abr - tim*abi;
    tim = tre*abi + tim*abr;
    tre = t2;
  }
}

// ---------------------------------------------------------------------------
// K2: Z + fused scan. One block per (b,d). Thread (n=tid&63, cg=tid>>6)
// accumulates 8 chunks in registers (1 W-read per 16 fma). Then wave 0 does
// the 32-step chunk scan in-block (k2b kernel eliminated) and writes S_c
// (state BEFORE chunk c) to global.
// ---------------------------------------------------------------------------
__global__ __launch_bounds__(256, 2) void k2_zscan(
    const float* __restrict__ u, const float2* __restrict__ Abar,
    const float2* __restrict__ Bbar, float2* __restrict__ S) {
  int bid = blockIdx.x;
  int b = bid & 7, d = bid >> 3;       // b -> XCD: u[b] slice stays L2-local
  int tid = threadIdx.x;
  __shared__ float2 Wl[TT][NN];        // 32 KB  W[s][n] = Abar^(63-s)*Bbar
  __shared__ float  ul[LL];            // 8 KB
  __shared__ float2 Zl[CC][NN];        // 16 KB
  if (tid < 64) {                      // wave 0 builds W while others stage u
    float2 a = Abar[d * NN + tid];
    float2 w = Bbar[d * NN + tid];
    for (int s = TT - 1; s >= 0; --s) { Wl[s][tid] = w; w = cmul(w, a); }
  } else {
    for (int i = tid - 64; i < LL; i += 192)
      ul[i] = u[((size_t)b * LL + i) * DD + d];
  }
  __syncthreads();
  int n = tid & 63, cg = tid >> 6;
  int c0 = cg * 8;
  float2 acc[8];
  #pragma unroll
  for (int i = 0; i < 8; ++i) acc[i] = make_float2(0.f, 0.f);
  #pragma unroll 4
  for (int s = 0; s < TT; ++s) {
    float2 w = Wl[s][n];               // one b64 per wave (lane-strided, free)
    #pragma unroll
    for (int i = 0; i < 8; ++i) {
      float uv = ul[(c0 + i) * TT + s];  // broadcast
      acc[i].x = fmaf(w.x, uv, acc[i].x);
      acc[i].y = fmaf(w.y, uv, acc[i].y);
    }
  }
  #pragma unroll
  for (int i = 0; i < 8; ++i) Zl[c0 + i][n] = acc[i];
  __syncthreads();
  if (tid < 64) {                      // fused scan, one wave
    float2 a = Abar[d * NN + tid];
    float2 p = a;
    #pragma unroll
    for (int q = 0; q < 6; ++q) p = cmul(p, p);   // wrong: gives a^64 after 6 squarings from a
    // note: p started at a, 6 squarings -> a^64. (a->a^2->a^4->...->a^64)
    float2 s = make_float2(0.f, 0.f);
    for (int c = 0; c < CC; ++c) {
      float2 z = Zl[c][tid];
      S[((size_t)(b * CC + c) * DD + d) * NN + tid] = s;
      float2 ps = cmul(p, s);
      s = make_float2(ps.x + z.x, ps.y + z.y);
    }
  }
}

// ---------------------------------------------------------------------------
// K3a: cross term ycross[d][pair][r] = Re(sum_n G[r][n]*S[pair][n]),
// G[r][n] = C*Abar^(r+1). One block per d. 8x8 register tile per thread:
// 8 pairs (stride 32 -> LDS lane-stride 8B, conflict-free) x 8 r (wave-
// uniform -> broadcast G reads). 16 LDS b64 per 128 fma.
// ---------------------------------------------------------------------------
__global__ __launch_bounds__(256, 2) void k3a_cross(
    const float2* __restrict__ Abar, const float* __restrict__ C_re,
    const float* __restrict__ C_im, const float2* __restrict__ S,
    float* __restrict__ ycross) {
  int d = blockIdx.x, tid = threadIdx.x;
  __shared__ float2 Gl[NN][TT];        // 32 KB  [n][r]
  __shared__ float2 Sl[16][256];       // 32 KB  [k][pair]
  if (tid < 64) {
    int n = tid;
    float2 a = Abar[d * NN + n];
    float2 g = cmul(make_float2(C_re[d*NN+n], C_im[d*NN+n]), a);
    for (int r = 0; r < TT; ++r) { Gl[n][r] = g; g = cmul(g, a); }
  }
  int tp = tid & 31, tr = tid >> 5;
  float acc[8][8];
  #pragma unroll
  for (int i = 0; i < 8; ++i)
    #pragma unroll
    for (int j = 0; j < 8; ++j) acc[i][j] = 0.f;
  for (int k0 = 0; k0 < NN; k0 += 16) {
    __syncthreads();                   // prev readers done (also G-build, 1st)
    {                                  // stage S[k0..k0+15][all 256 pairs]
      const float4* src = (const float4*)(S + ((size_t)tid * DD + d) * NN + k0);
      #pragma unroll
      for (int q = 0; q < 8; ++q) {
        float4 v = src[q];
        Sl[2*q  ][tid] = make_float2(v.x, v.y);
        Sl[2*q+1][tid] = make_float2(v.z, v.w);
      }
    }
    __syncthreads();
    #pragma unroll 2
    for (int k = 0; k < 16; ++k) {
      float2 sv[8], gv[8];
      #pragma unroll
      for (int i = 0; i < 8; ++i) sv[i] = Sl[k][tp + 32*i];
      #pragma unroll
      for (int j = 0; j < 8; ++j) gv[j] = Gl[k0 + k][tr*8 + j];  // broadcast
      #pragma unroll
      for (int i = 0; i < 8; ++i)
        #pragma unroll
        for (int j = 0; j < 8; ++j) {
          acc[i][j] = fmaf(sv[i].x, gv[j].x, acc[i][j]);
          acc[i][j] = fmaf(-sv[i].y, gv[j].y, acc[i][j]);
        }
    }
  }
  #pragma unroll
  for (int i = 0; i < 8; ++i) {
    float* yp = ycross + ((size_t)d * 256 + tp + 32*i) * TT + tr*8;
    *(float4*)(yp)     = make_float4(acc[i][0], acc[i][1], acc[i][2], acc[i][3]);
    *(float4*)(yp + 4) = make_float4(acc[i][4], acc[i][5], acc[i][6], acc[i][7]);
  }
}

// ---------------------------------------------------------------------------
// K3b: local causal 64-tap conv + cross term, coalesced y writes.
// Sliding 8-r register window over zero-padded u rows: 2 LDS b32 per 8 fma,
// all window indices static (unroll-by-8 rotation).
// ---------------------------------------------------------------------------
__global__ __launch_bounds__(256, 2) void k3b_out(
    const float* __restrict__ u, const float* __restrict__ KlocT,
    const float* __restrict__ ycross, float* __restrict__ y) {
  int bid = blockIdx.x;
  int d8 = bid & 7;
  int c  = (bid >> 3) & (CC - 1);
  int b  = bid >> 8;
  int d0 = d8 * 64;
  int tid = threadIdx.x;
  int dd = tid & 63, rq = tid >> 6;    // rq 0..3 (wave id)
  __shared__ float ulp[128][64];       // 32 KB: ulp[63+t][dd]=u[cT+t], rows<63 = 0
  __shared__ float Ktl[TT][64];        // 16 KB
  __shared__ float ycl[64][65];        // 16.25 KB (pad: 2-way only)
  for (int i = tid; i < 63 * 64; i += 256)
    ulp[i >> 6][i & 63] = 0.f;
  for (int i = tid; i < TT * 64; i += 256) {
    int s = i >> 6, e = i & 63;
    ulp[63 + s][e] = u[((size_t)b * LL + c * TT + s) * DD + d0 + e];
    Ktl[s][e] = KlocT[s * DD + d0 + e];
  }
  for (int i = tid; i < 64 * TT; i += 256) {
    int e = i >> 6, r = i & 63;
    ycl[e][r] = ycross[((size_t)(d0 + e) * 256 + b * CC + c) * TT + r];
  }
  __syncthreads();
  #pragma unroll 1
  for (int pass = 0; pass < 2; ++pass) {
    int rg = rq + 4 * pass;            // wave-uniform
    int r0 = rg * 8;
    float acc[8], w[8];
    #pragma unroll
    for (int j = 0; j < 8; ++j) acc[j] = ycl[dd][r0 + j];
    #pragma unroll
    for (int j = 0; j < 8; ++j) w[j] = ulp[63 + r0 + j][dd];
    // m = 0 .. r0+7 (multiple of 8 steps); u[r-m]=0 for r<m via zero rows
    for (int m0 = 0; m0 <= r0; m0 += 8) {
      #pragma unroll
      for (int mm = 0; mm < 8; ++mm) {
        float kv = Ktl[m0 + mm][dd];
        #pragma unroll
        for (int j = 0; j < 8; ++j)
          acc[j] = fmaf(kv, w[(j - mm) & 7], acc[j]);
        w[(7 - mm) & 7] = ulp[63 + r0 - 1 - (m0 + mm)][dd];  // refill (>=55)
      }
    }
    #pragma unroll
    for (int j = 0; j < 8; ++j)
      y[((size_t)b * LL + c * TT + r0 + j) * DD + d0 + dd] = acc[j];
  }
}

extern "C" void kernel_launch(void* const* d_in, const int* in_sizes, int n_in,
                              void* d_out, int out_size, void* d_ws, size_t ws_size,
                              hipStream_t stream) {
  const float* u      = (const float*)d_in[0];
  const float* A_re   = (const float*)d_in[1];
  const float* A_im   = (const float*)d_in[2];
  const float* C_re   = (const float*)d_in[3];
  const float* C_im   = (const float*)d_in[4];
  const float* log_dt = (const float*)d_in[5];
  float* y  = (float*)d_out;
  float* ws = (float*)d_ws;

  // ws layout (floats): S (B*C*D*N f2 = 67.1MB), ycross (33.6MB), Abar, Bbar, KlocT
  float2* S      = (float2*)ws;
  float*  ycross = ws + (size_t)2 * BB * CC * DD * NN;
  float2* Abar   = (float2*)(ycross + (size_t)DD * BB * CC * TT);
  float2* Bbar   = Abar + DD * NN;
  float*  KlocT  = (float*)(Bbar + DD * NN);

  k1_setup <<<DD,               64,  0, stream>>>(A_re, A_im, C_re, C_im, log_dt,
                                                  Abar, Bbar, KlocT);
  k2_zscan <<<BB * DD,          256, 0, stream>>>(u, Abar, Bbar, S);
  k3a_cross<<<DD,               256, 0, stream>>>(Abar, C_re, C_im, S, ycross);
  k3b_out  <<<BB * CC * (DD/64),256, 0, stream>>>(u, KlocT, ycross, y);
}

// Round 3
// 148.410 us; speedup vs baseline: 1.3927x; 1.0580x over previous
//
#include <hip/hip_runtime.h>

#define BB 8
#define LL 2048
#define DD 512
#define NN 64
#define TT 64
#define CC 32   // LL/TT chunks

__device__ __forceinline__ float2 cmul(float2 a, float2 b) {
  return make_float2(a.x*b.x - a.y*b.y, a.x*b.y + a.y*b.x);
}

// ---------------------------------------------------------------------------
// K1: per-d setup. 64 threads = one wave, lane = n.
// Abar=exp(dt*A), Bbar=dt*(Abar-1+eps)/(dt*A+eps),
// K_locT[m][d] = Re(sum_n C*Abar^m*Bbar), m=0..63 (transposed for coalescing).
// ---------------------------------------------------------------------------
__global__ __launch_bounds__(64) void k1_setup(
    const float* __restrict__ A_re, const float* __restrict__ A_im,
    const float* __restrict__ C_re, const float* __restrict__ C_im,
    const float* __restrict__ log_dt,
    float2* __restrict__ Abar, float2* __restrict__ Bbar,
    float* __restrict__ KlocT) {
  int d = blockIdx.x, n = threadIdx.x;
  int idx = d * NN + n;
  float dt  = expf(log_dt[d]);
  float dre = dt * A_re[idx], dim = dt * A_im[idx];
  float er  = expf(dre);
  float abr = er * cosf(dim), abi = er * sinf(dim);
  const float eps = 1e-8f;
  float nre = abr - 1.0f + eps, nim = abi;
  float qre = dre + eps,        qim = dim;
  float inv = 1.0f / (qre*qre + qim*qim);
  float bbr = dt * (nre*qre + nim*qim) * inv;
  float bbi = dt * (nim*qre - nre*qim) * inv;
  Abar[idx] = make_float2(abr, abi);
  Bbar[idx] = make_float2(bbr, bbi);
  float ccr = C_re[idx], cci = C_im[idx];
  float tre = ccr*bbr - cci*bbi;
  float tim = ccr*bbi + cci*bbr;
  for (int m = 0; m < TT; ++m) {
    float v = tre;
    #pragma unroll
    for (int off = 32; off > 0; off >>= 1) v += __shfl_down(v, off, 64);
    if (n == 0) KlocT[m * DD + d] = v;
    float t2 = tre*abr - tim*abi;
    tim = tre*abi + tim*abr;
    tre = t2;
  }
}

// ---------------------------------------------------------------------------
// K2 fused: Z (w-chain in registers) + in-block chunk scan + cross-term GEMM.
// One block per (b,d). Phases:
//   A: build Gst[n][r] = C*a^(r+1) (all 4 waves) + gather-stage u column
//   B: Z_c = sum_s a^(63-s)*Bbar*u[cT+s]; wave wv owns chunks wv*8..wv*8+7
//   C: 32-step scan in LDS (wave 0): Zs[c] <- S_c
//   D: ycross[c][r] = Re(sum_n Gst[n][r]*S_c[n]); lane=r, conflict-free
// LDS 48.5KB (ul aliased under Zs) -> 3 blocks/CU.
// ---------------------------------------------------------------------------
__global__ __launch_bounds__(256, 3) void k2_fused(
    const float* __restrict__ u, const float2* __restrict__ Abar,
    const float2* __restrict__ Bbar, const float* __restrict__ C_re,
    const float* __restrict__ C_im, float* __restrict__ ycross) {
  int bid = blockIdx.x;
  int b = bid & 7, d = bid >> 3;       // b = XCD: u[b] slice stays L2-local
  int tid = threadIdx.x;
  int n = tid & 63;
  int wv = tid >> 6;

  __shared__ __align__(16) char smem[16*1024 + NN*65*8];
  float*  ul  = (float*)smem;                 // [0,8KB)  live: phase A-B
  float2* Zs  = (float2*)smem;                // [0,16KB) live: post-B
  float2* Gst = (float2*)(smem + 16*1024);    // [n*65+r] 33.3KB

  float2 a = Abar[(size_t)d*NN + n];

  // --- A0: Gst build (wave wv -> r in [wv*16, wv*16+16))
  {
    float2 a2 = cmul(a,a), a4 = cmul(a2,a2), a8 = cmul(a4,a4), a16 = cmul(a8,a8);
    float2 base = a;
    for (int q = 0; q < wv; ++q) base = cmul(base, a16);   // a^(16*wv+1)
    float2 cc = make_float2(C_re[(size_t)d*NN+n], C_im[(size_t)d*NN+n]);
    float2 g = cmul(cc, base);
    int r0 = wv * 16;
    #pragma unroll
    for (int j = 0; j < 16; ++j) { Gst[(size_t)n*65 + r0 + j] = g; g = cmul(g, a); }
  }
  // --- A1: stage u column (strided gather, L2-resident per XCD)
  for (int i = tid; i < LL; i += 256)
    ul[i] = u[((size_t)b*LL + i)*DD + d];
  __syncthreads();

  // --- B: Z for my 8 chunks; w = Abar^(63-s)*Bbar walked in registers
  float2 acc[8];
  #pragma unroll
  for (int i = 0; i < 8; ++i) acc[i] = make_float2(0.f, 0.f);
  {
    float2 w = Bbar[(size_t)d*NN + n];        // W[s=63]
    int c0 = wv * 8;
    #pragma unroll 4
    for (int s1 = 63; s1 >= 1; s1 -= 2) {
      float2 wa = cmul(w, a);                 // W[s1-1]
      #pragma unroll
      for (int i = 0; i < 8; ++i) {
        float2 uv = *(const float2*)&ul[(c0+i)*TT + (s1-1)];  // (u[s1-1],u[s1])
        acc[i].x = fmaf(wa.x, uv.x, fmaf(w.x, uv.y, acc[i].x));
        acc[i].y = fmaf(wa.y, uv.x, fmaf(w.y, uv.y, acc[i].y));
      }
      w = cmul(wa, a);
    }
  }
  __syncthreads();                            // all ul reads done
  {
    int c0 = wv * 8;
    #pragma unroll
    for (int i = 0; i < 8; ++i) Zs[(size_t)(c0+i)*NN + n] = acc[i];
  }
  __syncthreads();

  // --- C: scan (wave 0 only): Zs[c] := S_c; S_{c+1} = a^64*S_c + Z_c
  if (wv == 0) {
    float2 a2 = cmul(a,a), a4 = cmul(a2,a2), a8 = cmul(a4,a4), a16 = cmul(a8,a8);
    float2 a32 = cmul(a16,a16), a64 = cmul(a32,a32);
    float2 s = make_float2(0.f, 0.f);
    for (int c = 0; c < CC; ++c) {
      float2 z = Zs[(size_t)c*NN + n];
      Zs[(size_t)c*NN + n] = s;
      float2 ps = cmul(a64, s);
      s = make_float2(ps.x + z.x, ps.y + z.y);
    }
  }
  __syncthreads();

  // --- D: ycross[c][r] = Re(sum_n Gst[n][r] * S_c[n]); lane = r
  {
    int r = n, c0 = wv * 8;
    float acc2[8];
    #pragma unroll
    for (int i = 0; i < 8; ++i) acc2[i] = 0.f;
    #pragma unroll 2
    for (int nn = 0; nn < NN; ++nn) {
      float2 g = Gst[(size_t)nn*65 + r];      // lane-stride 8B, conflict-free
      #pragma unroll
      for (int i = 0; i < 8; ++i) {
        float2 s = Zs[(size_t)(c0+i)*NN + nn];  // broadcast
        acc2[i] = fmaf(g.x, s.x, fmaf(-g.y, s.y, acc2[i]));
      }
    }
    float* yp = ycross + ((size_t)d*256 + b*CC) * TT;
    #pragma unroll
    for (int i = 0; i < 8; ++i)
      yp[(size_t)(c0+i)*TT + r] = acc2[i];    // coalesced 256B/wave
  }
}

// ---------------------------------------------------------------------------
// K3b: local causal 64-tap conv + cross term, coalesced y writes.
// Sliding 8-r register window over zero-padded u rows.
// ---------------------------------------------------------------------------
__global__ __launch_bounds__(256, 2) void k3b_out(
    const float* __restrict__ u, const float* __restrict__ KlocT,
    const float* __restrict__ ycross, float* __restrict__ y) {
  int bid = blockIdx.x;
  int d8 = bid & 7;
  int c  = (bid >> 3) & (CC - 1);
  int b  = bid >> 8;
  int d0 = d8 * 64;
  int tid = threadIdx.x;
  int dd = tid & 63, rq = tid >> 6;
  __shared__ float ulp[128][64];       // ulp[63+t][dd]=u[cT+t], rows<63 = 0
  __shared__ float Ktl[TT][64];
  __shared__ float ycl[64][65];
  for (int i = tid; i < 63 * 64; i += 256)
    ulp[i >> 6][i & 63] = 0.f;
  for (int i = tid; i < TT * 64; i += 256) {
    int s = i >> 6, e = i & 63;
    ulp[63 + s][e] = u[((size_t)b * LL + c * TT + s) * DD + d0 + e];
    Ktl[s][e] = KlocT[s * DD + d0 + e];
  }
  for (int i = tid; i < 64 * TT; i += 256) {
    int e = i >> 6, r = i & 63;
    ycl[e][r] = ycross[((size_t)(d0 + e) * 256 + b * CC + c) * TT + r];
  }
  __syncthreads();
  #pragma unroll 1
  for (int pass = 0; pass < 2; ++pass) {
    int rg = rq + 4 * pass;            // wave-uniform
    int r0 = rg * 8;
    float acc[8], w[8];
    #pragma unroll
    for (int j = 0; j < 8; ++j) acc[j] = ycl[dd][r0 + j];
    #pragma unroll
    for (int j = 0; j < 8; ++j) w[j] = ulp[63 + r0 + j][dd];
    for (int m0 = 0; m0 <= r0; m0 += 8) {
      #pragma unroll
      for (int mm = 0; mm < 8; ++mm) {
        float kv = Ktl[m0 + mm][dd];
        #pragma unroll
        for (int j = 0; j < 8; ++j)
          acc[j] = fmaf(kv, w[(j - mm) & 7], acc[j]);
        w[(7 - mm) & 7] = ulp[63 + r0 - 1 - (m0 + mm)][dd];
      }
    }
    #pragma unroll
    for (int j = 0; j < 8; ++j)
      y[((size_t)b * LL + c * TT + r0 + j) * DD + d0 + dd] = acc[j];
  }
}

extern "C" void kernel_launch(void* const* d_in, const int* in_sizes, int n_in,
                              void* d_out, int out_size, void* d_ws, size_t ws_size,
                              hipStream_t stream) {
  const float* u      = (const float*)d_in[0];
  const float* A_re   = (const float*)d_in[1];
  const float* A_im   = (const float*)d_in[2];
  const float* C_re   = (const float*)d_in[3];
  const float* C_im   = (const float*)d_in[4];
  const float* log_dt = (const float*)d_in[5];
  float* y  = (float*)d_out;
  float* ws = (float*)d_ws;

  // ws layout (floats): ycross (D*256*T = 33.6MB), Abar, Bbar, KlocT
  float*  ycross = ws;
  float2* Abar   = (float2*)(ycross + (size_t)DD * BB * CC * TT);
  float2* Bbar   = Abar + DD * NN;
  float*  KlocT  = (float*)(Bbar + DD * NN);

  k1_setup<<<DD,                64,  0, stream>>>(A_re, A_im, C_re, C_im, log_dt,
                                                  Abar, Bbar, KlocT);
  k2_fused<<<BB * DD,           256, 0, stream>>>(u, Abar, Bbar, C_re, C_im, ycross);
  k3b_out <<<BB * CC * (DD/64), 256, 0, stream>>>(u, KlocT, ycross, y);
}